// Round 16
// baseline (70.868 us; speedup 1.0000x reference)
//
#include <hip/hip_runtime.h>
#include <math.h>

// LightconvLayer: x (T,B,C) f32, weight (H,K) f32 -> out (T,B,C) f32
// out[t,b,c] = sum_k softmax(weight[c/64])[k] * x[t+k-30, b, c] (zero-pad left)
//
// R16: DRAM-ROW-LINEAR blocks (H6 test). All prior designs walked t at
// 32 KB stride with 256B-1KB pieces -> every HBM access opens a new DRAM
// row (~50% efficiency; matches the 3.0-3.7 TB/s plateau of R1-R15, vs
// 6.3-6.7 TB/s for linear-walk fill/copy). Exploit: in (T,B,C) layout a
// b-PAIR slice of one t-row is 8 KB CONTIGUOUS.
//  - block = 512 thr = (8-row t-strip, b-pair); thread = (b-off, c-quad f4)
//  - per t: one 8 KB contiguous block load (x) / store (out); t sequential
//  - single-shot: float4 window xv[38] in registers (152 VGPR) + per-lane
//    taps (31) ~ 195 total; launch_bounds(512,2) caps 256 -> no spill
//  - no LDS, no barriers, no inline asm; halo re-reads served by L3
#define T_LEN 2048
#define B_SZ  8
#define C_SZ  1024
#define NH    16
#define KW    31
#define HALO  (KW - 1)        // 30
#define TT    8               // t-rows per block
#define WIN   (TT + HALO)     // 38
#define NSTRIP (T_LEN / TT)   // 256
#define ROWSTRIDE (B_SZ * C_SZ)  // 8192 floats between t rows

template <bool CLIP>
__device__ __forceinline__ void conv_body(const float* __restrict__ xp,
                                          float* __restrict__ op,
                                          const float* __restrict__ wk,
                                          int tb) {
  // window rows tb-30 .. tb+7: 38 independent 8KB-contiguous block loads
  float4 xv[WIN];
#pragma unroll
  for (int i = 0; i < WIN; ++i) {
    const int t = tb - HALO + i;   // block-uniform sign
    if (CLIP) {
      xv[i] = (t >= 0) ? *(const float4*)&xp[(size_t)t * ROWSTRIDE]
                       : make_float4(0.f, 0.f, 0.f, 0.f);
    } else {
      xv[i] = *(const float4*)&xp[(size_t)t * ROWSTRIDE];
    }
  }
  // 8 outputs, all indices compile-time (rule #20)
#pragma unroll
  for (int o = 0; o < TT; ++o) {
    float ax = 0.f, ay = 0.f, az = 0.f, aw = 0.f;
#pragma unroll
    for (int k = 0; k < KW; ++k) {
      const float wv = wk[k];
      ax = fmaf(wv, xv[o + k].x, ax);
      ay = fmaf(wv, xv[o + k].y, ay);
      az = fmaf(wv, xv[o + k].z, az);
      aw = fmaf(wv, xv[o + k].w, aw);
    }
    *(float4*)&op[(size_t)o * ROWSTRIDE] = make_float4(ax, ay, az, aw);
  }
}

__global__ __launch_bounds__(512, 2) void lightconv_kernel(
    const float* __restrict__ x, const float* __restrict__ weight,
    float* __restrict__ out) {
  const int tid = threadIdx.x;

  const int strip = blockIdx.x;          // 0..255
  const int bpair = blockIdx.y;          // 0..3
  const int tb    = strip * TT;
  const int b     = 2 * bpair + (tid >> 8);   // batch
  const int cq    = tid & 255;                // c-quad 0..255
  const int c0    = 4 * cq;

  // --- taps: per-lane head, softmax in VGPRs ---
  const int head = cq >> 4;              // c0/64
  float wv[KW];
  float m = -1e30f;
#pragma unroll
  for (int k = 0; k < KW; ++k) {
    wv[k] = weight[head * KW + k];
    m = fmaxf(m, wv[k]);
  }
  float s = 0.f;
#pragma unroll
  for (int k = 0; k < KW; ++k) {
    wv[k] = expf(wv[k] - m);
    s += wv[k];
  }
  const float inv = 1.f / s;
  float wk[KW];
#pragma unroll
  for (int k = 0; k < KW; ++k) wk[k] = wv[k] * inv;

  const float* xp = x + (size_t)b * C_SZ + c0;
  float* op = out + ((size_t)tb * B_SZ + b) * C_SZ + c0;

  if (tb >= HALO) {
    conv_body<false>(xp, op, wk, tb);
  } else {
    conv_body<true>(xp, op, wk, tb);
  }
}

extern "C" void kernel_launch(void* const* d_in, const int* in_sizes, int n_in,
                              void* d_out, int out_size, void* d_ws, size_t ws_size,
                              hipStream_t stream) {
  const float* x = (const float*)d_in[0];      // (T,B,C) f32
  const float* w = (const float*)d_in[1];      // (H,K) f32
  float* out = (float*)d_out;                  // (T,B,C) f32
  (void)in_sizes; (void)n_in; (void)out_size; (void)d_ws; (void)ws_size;

  dim3 grid(NSTRIP, B_SZ / 2);                 // (256, 4) = 1024 blocks
  dim3 block(512);
  lightconv_kernel<<<grid, block, 0, stream>>>(x, w, out);
}

// Round 17
// 32.311 us; speedup vs baseline: 2.1933x; 2.1933x over previous
//
#include <hip/hip_runtime.h>
#include <math.h>

// LightconvLayer: x (T,B,C) f32, weight (H,K) f32 -> out (T,B,C) f32
// out[t,b,c] = sum_k softmax(weight[c/64])[k] * x[t+k-30, b, c] (zero-pad left)
//
// R17 = R11 champion (wave-autonomous ring, depth-2 counted vmcnt, sliding
// register window, no barriers) widened to 4 channels/lane (last untested
// lever; width series: 4B=30.8us, 8B=30.2us, 16B=?):
//  - wave owns (b, 256 ch = 4 heads, 64-row chunk); 8 tiles of TT=8
//  - staging: width-16 gload_lds = ONE full 1 KB row/instr; 8 instr/tile;
//    depth-2 in flight = 16 KB/wave, 4 blocks/CU -> 64 KB/CU (highest yet)
//  - stores: global_store_dwordx4 (1 KB/wave-instr); ring reads ds_read_b128
//  - ring[32][256] f32 = 32 KB; 1024 blocks = 4/CU (LDS 128KB/160KB)
//  - vmcnt ledger (in-order, L=8,S=8 per tile): j0=16, j1=24, j2..5=32,
//    j6=24, j7=16
//  - bijective XCD swizzle keeps t-neighbor chunks (halo sharers) on the
//    same XCD's L2 (R16 dropped this and FETCH blew up to 154 MB)
#define T_LEN 2048
#define B_SZ  8
#define C_SZ  1024
#define NH    16
#define KW    31
#define HALO  (KW - 1)        // 30
#define TT    8
#define CHUNK 64              // rows per wave
#define NTILE (CHUNK / TT)    // 8
#define RING  32
#define WIN   (TT + HALO)     // 38
#define CGW   256             // channels per wave (4 per lane)
#define ROWSTRIDE (B_SZ * C_SZ)  // 8192 floats between t rows

#define GLOBAL_AS(p) ((const __attribute__((address_space(1))) void*)(p))
#define LDS_AS(p)    ((__attribute__((address_space(3))) void*)(p))

__global__ __launch_bounds__(64, 2) void lightconv_kernel(
    const float* __restrict__ x, const float* __restrict__ weight,
    float* __restrict__ out) {
  __shared__ float ring[RING][CGW];  // 32 KB, wave-private (1 wave/block)
  const int lane = threadIdx.x;

  // bijective XCD swizzle over the 128 x-blocks (128 % 8 == 0): XCD k owns
  // lin in [16k,16k+16) -> 16 CONSECUTIVE t-chunks of one channel group.
  const int bx   = blockIdx.x;
  const int lin  = (bx & 7) * 16 + (bx >> 3);
  const int tc   = lin & 31;         // t-chunk 0..31
  const int cgrp = lin >> 5;         // 256-ch group 0..3
  const int b    = blockIdx.y;
  const int c0   = cgrp * CGW;
  const int tb   = tc * CHUNK;       // tb % 32 == 0 -> compile-time slots

  // --- taps: per-lane (4 heads per wave). load + softmax in VGPRs ---
  const int head = cgrp * 4 + (lane >> 4);
  float wv[KW];
  float m = -1e30f;
#pragma unroll
  for (int k = 0; k < KW; ++k) {
    wv[k] = weight[head * KW + k];
    m = fmaxf(m, wv[k]);
  }
  float s = 0.f;
#pragma unroll
  for (int k = 0; k < KW; ++k) {
    wv[k] = expf(wv[k] - m);
    s += wv[k];
  }
  const float inv = 1.f / s;
  float wk[KW];
#pragma unroll
  for (int k = 0; k < KW; ++k) wk[k] = wv[k] * inv;

  const float* xbase = x + (size_t)b * C_SZ + c0;
  const float* xch   = xbase + 4 * lane;  // per-lane 4-channel base
  const int lane_off = lane * 4;          // floats: lane covers ch 4l..4l+3

  // --- prologue ---
  // halo rows tb-30..tb-1 -> registers xv[0..29] (dwordx4)
  float4 xv[WIN];
  if (tb == 0) {
#pragma unroll
    for (int i = 0; i < HALO; ++i) xv[i] = make_float4(0.f, 0.f, 0.f, 0.f);
  } else {
#pragma unroll
    for (int i = 0; i < HALO; ++i) {
      xv[i] = *(const float4*)&xch[(size_t)(tb - HALO + i) * ROWSTRIDE];
    }
  }
  __builtin_amdgcn_sched_barrier(0);  // keep halo loads oldest in the queue

  // stage L(0),L(1): rows tb..tb+15 -> slots 0..15 (one 1 KB row per instr)
#pragma unroll
  for (int r = 0; r < 16; ++r) {
    const float* gp = xbase + (size_t)(tb + r) * ROWSTRIDE + lane_off;
    __builtin_amdgcn_global_load_lds(GLOBAL_AS(gp), LDS_AS(&ring[r][0]),
                                     16, 0, 0);
  }

  // --- 8 tiles, fully unrolled, no barriers, counted own-vmcnt ---
#pragma unroll
  for (int j = 0; j < NTILE; ++j) {
    const int tstart = tb + j * TT;

    __builtin_amdgcn_sched_barrier(0);  // tile-top fence
    // stage L(j+2): rows tstart+16..23 -> slots (8j+16+r)&31 (compile-time)
    if (j <= NTILE - 3) {
#pragma unroll
      for (int r = 0; r < TT; ++r) {
        const float* gp =
            xbase + (size_t)(tstart + 2 * TT + r) * ROWSTRIDE + lane_off;
        __builtin_amdgcn_global_load_lds(
            GLOBAL_AS(gp), LDS_AS(&ring[(8 * j + 16 + r) & (RING - 1)][0]),
            16, 0, 0);
      }
    }
    // counted wait: guarantee L(j) retired (in-order vmem retirement;
    // steady newer-than-L(j) = S(j-2)8 + L(j+1)8 + S(j-1)8 + L(j+2)8 = 32)
    if (j == 0)                asm volatile("s_waitcnt vmcnt(16)" ::: "memory");
    else if (j == 1)           asm volatile("s_waitcnt vmcnt(24)" ::: "memory");
    else if (j == NTILE - 2)   asm volatile("s_waitcnt vmcnt(24)" ::: "memory");
    else if (j == NTILE - 1)   asm volatile("s_waitcnt vmcnt(16)" ::: "memory");
    else                       asm volatile("s_waitcnt vmcnt(32)" ::: "memory");
    __builtin_amdgcn_sched_barrier(0);  // rule #18: pin ds_reads below

    // read tile j's 8 new rows once (ds_read_b128, imm slot offsets)
#pragma unroll
    for (int i = 0; i < TT; ++i) {
      const float4* rp = (const float4*)&ring[(8 * j + i) & (RING - 1)][0];
      xv[HALO + i] = rp[lane];
    }
    // compute + store 8 outputs (dwordx4, 1 KB/wave-instr)
    float* opb = out + ((size_t)tstart * B_SZ + b) * C_SZ + c0 + 4 * lane;
#pragma unroll
    for (int o = 0; o < TT; ++o) {
      float ax = 0.f, ay = 0.f, az = 0.f, aw = 0.f;
#pragma unroll
      for (int k = 0; k < KW; ++k) {
        const float w = wk[k];
        ax = fmaf(w, xv[o + k].x, ax);
        ay = fmaf(w, xv[o + k].y, ay);
        az = fmaf(w, xv[o + k].z, az);
        aw = fmaf(w, xv[o + k].w, aw);
      }
      *(float4*)&opb[(size_t)o * ROWSTRIDE] = make_float4(ax, ay, az, aw);
    }
    // slide window by TT (full unroll -> pure register renaming)
#pragma unroll
    for (int i = 0; i < HALO; ++i) xv[i] = xv[i + TT];
  }
}

extern "C" void kernel_launch(void* const* d_in, const int* in_sizes, int n_in,
                              void* d_out, int out_size, void* d_ws, size_t ws_size,
                              hipStream_t stream) {
  const float* x = (const float*)d_in[0];      // (T,B,C) f32
  const float* w = (const float*)d_in[1];      // (H,K) f32
  float* out = (float*)d_out;                  // (T,B,C) f32
  (void)in_sizes; (void)n_in; (void)out_size; (void)d_ws; (void)ws_size;

  dim3 grid((C_SZ / CGW) * (T_LEN / CHUNK), B_SZ);  // (128, 8) = 1024 blocks
  dim3 block(64);
  lightconv_kernel<<<grid, block, 0, stream>>>(x, w, out);
}

// Round 18
// 30.366 us; speedup vs baseline: 2.3338x; 1.0641x over previous
//
#include <hip/hip_runtime.h>
#include <math.h>

// LightconvLayer: x (T,B,C) f32, weight (H,K) f32 -> out (T,B,C) f32
// out[t,b,c] = sum_k softmax(weight[c/64])[k] * x[t+k-30, b, c] (zero-pad left)
//
// CHAMPION (R11, 30.2 us): wave-autonomous LDS-ring pipeline, float2 lanes.
//  - wave owns (b, 128 ch = 2 heads, 64-row chunk); 8 tiles of TT=8
//  - stores: global_store_dwordx2; staging: width-16 gload_lds packs 2 rows
//    (1 KB contiguous) per instr; halo -> regs; sliding window xv[38] (f2)
//  - depth-2 prefetch, counted own-vmcnt (never drain), no barriers
// vmcnt ledger (in-order, L=4,S=8): j0=8, j1=16, j2..5=24, j6=20, j7=16
// slot safety mod 32: stage(j+2) slots (8j+16..23)&31 vs reads (8j..8j+7)&31
//
// Empirical wall (R0-R17): occupancy, store width, contiguity, prefetch
// depth, barriers, store-decoupled queues, DRAM-linear blocks all tested ->
// every design lands 30-39 us at ~3.1-3.8 TB/s effective. Pattern ceiling:
// 2048 streams x 32 KB-stride x ~1 KB granules = device-level DRAM scatter.
#define T_LEN 2048
#define B_SZ  8
#define C_SZ  1024
#define NH    16
#define KW    31
#define HALO  (KW - 1)        // 30
#define TT    8
#define CHUNK 64              // rows per wave
#define NTILE (CHUNK / TT)    // 8
#define RING  32
#define WIN   (TT + HALO)     // 38
#define CGW   128             // channels per wave
#define ROWSTRIDE (B_SZ * C_SZ)  // 8192 floats between t rows

#define GLOBAL_AS(p) ((const __attribute__((address_space(1))) void*)(p))
#define LDS_AS(p)    ((__attribute__((address_space(3))) void*)(p))

__global__ __launch_bounds__(64, 3) void lightconv_kernel(
    const float* __restrict__ x, const float* __restrict__ weight,
    float* __restrict__ out) {
  __shared__ float ring[RING][CGW];  // 16 KB, wave-private (1 wave/block)
  const int lane = threadIdx.x;

  const int cgrp = blockIdx.x & 7;   // 128-ch group (C/128 = 8)
  const int tc   = blockIdx.x >> 3;  // t-chunk 0..31
  const int b    = blockIdx.y;
  const int c0   = cgrp * CGW;
  const int tb   = tc * CHUNK;       // tb % 32 == 0 -> compile-time slots

  // --- taps: per-lane (2 heads per wave). load + softmax in VGPRs ---
  const int head = cgrp * 2 + (lane >> 5);
  float wv[KW];
  float m = -1e30f;
#pragma unroll
  for (int k = 0; k < KW; ++k) {
    wv[k] = weight[head * KW + k];
    m = fmaxf(m, wv[k]);
  }
  float s = 0.f;
#pragma unroll
  for (int k = 0; k < KW; ++k) {
    wv[k] = expf(wv[k] - m);
    s += wv[k];
  }
  const float inv = 1.f / s;
  float wk[KW];
#pragma unroll
  for (int k = 0; k < KW; ++k) wk[k] = wv[k] * inv;

  const float* xbase = x + (size_t)b * C_SZ + c0;
  const float* xch   = xbase + 2 * lane;  // per-lane channel pair base
  // staging offset: lane l -> row (l>>5), ch (l&31)*4 floats (16 B)
  const int lane_off = (lane >> 5) * ROWSTRIDE + (lane & 31) * 4;

  // --- prologue ---
  // halo rows tb-30..tb-1 -> registers xv[0..29] (float2, 512 B/instr)
  float2 xv[WIN];
  if (tb == 0) {
#pragma unroll
    for (int i = 0; i < HALO; ++i) xv[i] = make_float2(0.f, 0.f);
  } else {
#pragma unroll
    for (int i = 0; i < HALO; ++i) {
      xv[i] = *(const float2*)&xch[(size_t)(tb - HALO + i) * ROWSTRIDE];
    }
  }
  // stage L(0): rows tb..tb+7 -> slots 0..7; L(1): rows tb+8..15 -> slots 8..15
  // (each width-16 instr = 2 full 512 B rows = 1 KB contiguous)
#pragma unroll
  for (int r2 = 0; r2 < 8; ++r2) {
    const float* gp = xbase + (size_t)(tb + 2 * r2) * ROWSTRIDE + lane_off;
    __builtin_amdgcn_global_load_lds(GLOBAL_AS(gp), LDS_AS(&ring[2 * r2][0]),
                                     16, 0, 0);
  }

  // --- 8 tiles, fully unrolled, no barriers, counted own-vmcnt ---
#pragma unroll
  for (int j = 0; j < NTILE; ++j) {
    const int tstart = tb + j * TT;

    // stage L(j+2): rows tstart+16..23 -> slots (8j+16+2r2)&31 (compile-time)
    if (j <= NTILE - 3) {
#pragma unroll
      for (int r2 = 0; r2 < 4; ++r2) {
        const float* gp =
            xbase + (size_t)(tstart + 2 * TT + 2 * r2) * ROWSTRIDE + lane_off;
        __builtin_amdgcn_global_load_lds(
            GLOBAL_AS(gp), LDS_AS(&ring[(8 * j + 16 + 2 * r2) & (RING - 1)][0]),
            16, 0, 0);
      }
    }
    // counted wait: guarantee L(j) retired (in-order vmem retirement;
    // ledger: newer-than-L(j) = S(j-2)8 + L(j+1)4 + S(j-1)8 + L(j+2)4 = 24)
    if (j == 0)                asm volatile("s_waitcnt vmcnt(8)"  ::: "memory");
    else if (j == 1)           asm volatile("s_waitcnt vmcnt(16)" ::: "memory");
    else if (j == NTILE - 2)   asm volatile("s_waitcnt vmcnt(20)" ::: "memory");
    else if (j == NTILE - 1)   asm volatile("s_waitcnt vmcnt(16)" ::: "memory");
    else                       asm volatile("s_waitcnt vmcnt(24)" ::: "memory");
    __builtin_amdgcn_sched_barrier(0);  // rule #18: pin ds_reads below

    // read tile j's 8 new rows once (ds_read_b64, imm slot offsets)
#pragma unroll
    for (int i = 0; i < TT; ++i) {
      const float2* rp = (const float2*)&ring[(8 * j + i) & (RING - 1)][0];
      xv[HALO + i] = rp[lane];
    }
    // compute + store 8 outputs (dwordx2)
    float* opb = out + ((size_t)tstart * B_SZ + b) * C_SZ + c0 + 2 * lane;
#pragma unroll
    for (int o = 0; o < TT; ++o) {
      float ax = 0.f, ay = 0.f;
#pragma unroll
      for (int k = 0; k < KW; ++k) {
        ax = fmaf(wk[k], xv[o + k].x, ax);
        ay = fmaf(wk[k], xv[o + k].y, ay);
      }
      *(float2*)&opb[(size_t)o * ROWSTRIDE] = make_float2(ax, ay);
    }
    // slide window by TT (full unroll -> pure register renaming)
#pragma unroll
    for (int i = 0; i < HALO; ++i) xv[i] = xv[i + TT];
  }
}

extern "C" void kernel_launch(void* const* d_in, const int* in_sizes, int n_in,
                              void* d_out, int out_size, void* d_ws, size_t ws_size,
                              hipStream_t stream) {
  const float* x = (const float*)d_in[0];      // (T,B,C) f32
  const float* w = (const float*)d_in[1];      // (H,K) f32
  float* out = (float*)d_out;                  // (T,B,C) f32
  (void)in_sizes; (void)n_in; (void)out_size; (void)d_ws; (void)ws_size;

  dim3 grid((C_SZ / CGW) * (T_LEN / CHUNK), B_SZ);  // (256, 8) = 2048 waves
  dim3 block(64);
  lightconv_kernel<<<grid, block, 0, stream>>>(x, w, out);
}